// Round 1
// baseline (655.970 us; speedup 1.0000x reference)
//
#include <hip/hip_runtime.h>
#include <math.h>

namespace {
constexpr int cB   = 2;
constexpr int cDIM = 192;
constexpr int cNH  = 6;
constexpr int cHD  = 32;
constexpr int cWS  = 64;
constexpr int cH   = 256;
constexpr int cW   = 256;
constexpr int cRH  = 32;
constexpr int cL   = 1024;   // RH*RW windows
constexpr int cP   = 225;    // (2*8-1)^2
constexpr float cSCALE = 0.17677669529663688f; // 32^-0.5
}

// ---------------- Kernel 1: 8x8 window mean-pool of q,k channels ----------------
// pool layout: [b][l][384]  (c<192: q-mean, c>=192: k-mean)
__global__ void pool_kernel(const float* __restrict__ x, float* __restrict__ pool) {
    int blk = blockIdx.x;              // b*384*32 + c*32 + rh
    int rh = blk & 31;
    int c  = (blk >> 5) % 384;
    int b  = blk / (384 * 32);
    int tid = threadIdx.x;             // 256
    int i  = tid >> 5;                 // row in window 0..7
    int rw = tid & 31;                 // window col 0..31
    const float* row = x + (((size_t)(b * 576 + c)) * cH + rh * 8 + i) * cW + rw * 8;
    float4 a0 = *(const float4*)row;
    float4 a1 = *(const float4*)(row + 4);
    float s = a0.x + a0.y + a0.z + a0.w + a1.x + a1.y + a1.z + a1.w;
    __shared__ float red[8][33];
    red[i][rw] = s;
    __syncthreads();
    if (tid < 32) {
        float t = 0.f;
        #pragma unroll
        for (int k = 0; k < 8; ++k) t += red[k][tid];
        pool[((size_t)(b * cL) + rh * 32 + tid) * 384 + c] = t * (1.0f / 64.0f);
    }
}

// ---------------- Kernel 2: router (9-neighbor argmax) ----------------
// idxbuf[bl*2+0] = direction (0..8), idxbuf[bl*2+1] = target window index
__global__ void router_kernel(const float* __restrict__ pool, int* __restrict__ idxbuf) {
    int blk = blockIdx.x;              // b*L + l
    int l = blk & (cL - 1);
    int b = blk >> 10;
    int rh = l >> 5, rw = l & 31;
    int lane = threadIdx.x;            // 64 threads = 1 wave
    int ln[9];
    #pragma unroll
    for (int n = 0; n < 9; ++n) {
        int nh = rh + n / 3 - 1;
        int nw = rw + n % 3 - 1;
        nh = nh < 0 ? 1 : (nh > 31 ? 30 : nh);   // np.pad reflect, pad=1
        nw = nw < 0 ? 1 : (nw > 31 ? 30 : nw);
        ln[n] = nh * 32 + nw;
    }
    float acc[9] = {0,0,0,0,0,0,0,0,0};
    const float* qb = pool + ((size_t)(b * cL) + l) * 384;
    #pragma unroll
    for (int ci = 0; ci < 3; ++ci) {
        int c = lane + ci * 64;
        float q = qb[c];
        #pragma unroll
        for (int n = 0; n < 9; ++n)
            acc[n] += q * pool[((size_t)(b * cL) + ln[n]) * 384 + 192 + c];
    }
    #pragma unroll
    for (int n = 0; n < 9; ++n)
        #pragma unroll
        for (int off = 32; off > 0; off >>= 1)
            acc[n] += __shfl_down(acc[n], off);
    if (lane == 0) {
        acc[4] -= 100.0f;
        int bi = 0; float bv = acc[0];
        #pragma unroll
        for (int n = 1; n < 9; ++n) if (acc[n] > bv) { bv = acc[n]; bi = n; } // first-max
        idxbuf[blk * 2]     = bi;
        idxbuf[blk * 2 + 1] = ln[bi];
    }
}

// ---------------- Kernel 3: attention, one block per (b,l,h) ----------------
// LDS map (words): Vs[0,4096) Qs[4096,6144) Ks[6144,10240) ; Ps[4096,12544) overlays Q/K after QK ; pes[12544,12994)
__global__ __launch_bounds__(256, 2) void attn_kernel(
    const float* __restrict__ x, const float* __restrict__ pe,
    const int* __restrict__ idxbuf, float* __restrict__ out)
{
    __shared__ float smem[12996];
    float* Vs  = smem;
    float* Qs  = smem + 4096;
    float* Ks  = smem + 6144;
    float* Ps  = smem + 4096;
    float* pes = smem + 12544;

    int blk = blockIdx.x;              // h*2048 + b*1024 + l
    int h  = blk >> 11;
    int bl = blk & 2047;
    int b  = bl >> 10;
    int l  = bl & 1023;
    int rh = l >> 5, rw = l & 31;
    int tid = threadIdx.x;

    int dir  = idxbuf[bl * 2];
    int lwin = idxbuf[bl * 2 + 1];
    int rh2 = lwin >> 5, rw2 = lwin & 31;

    // stage relative-position bias rows for this head
    const float* pe_self = pe + (4 * cNH + h) * cP;
    const float* pe_dir  = pe + (dir * cNH + h) * cP;
    for (int t = tid; t < 2 * cP; t += 256)
        pes[t] = (t < cP) ? pe_self[t] : pe_dir[t - cP];

    // stage Q, K_self, K_dir, V_self, V_dir (64x32 tiles, swizzled col = (d + 4*(row>>3)) & 31)
    {
        int d = tid & 31;
        int i = tid >> 5;              // window row 0..7
        int dsw = (d + 4 * i) & 31;
        const size_t CHW = (size_t)cH * cW;
        const float* xb = x + (size_t)b * (3 * cDIM) * CHW;
        size_t off_self = (size_t)(rh  * 8 + i) * cW + rw  * 8;
        size_t off_dir  = (size_t)(rh2 * 8 + i) * cW + rw2 * 8;
        size_t cq = (size_t)(h * cHD + d) * CHW;
        size_t ck = cq + (size_t)cDIM * CHW;
        size_t cv = ck + (size_t)cDIM * CHW;
        const float* srcs[5] = { xb + cq + off_self, xb + ck + off_self, xb + ck + off_dir,
                                 xb + cv + off_self, xb + cv + off_dir };
        float* dsts[5] = { Qs, Ks, Ks + 2048, Vs, Vs + 2048 };
        #pragma unroll
        for (int m = 0; m < 5; ++m) {
            float4 a0 = *(const float4*)(srcs[m]);
            float4 a1 = *(const float4*)(srcs[m] + 4);
            float vv[8] = {a0.x,a0.y,a0.z,a0.w,a1.x,a1.y,a1.z,a1.w};
            float mult = (m == 0) ? cSCALE : 1.0f;
            float* dd = dsts[m] + dsw;
            #pragma unroll
            for (int j = 0; j < 8; ++j)
                dd[(i * 8 + j) * 32] = vv[j] * mult;
        }
    }
    __syncthreads();

    // thread tile: 4 rows (s0..s0+3) x 8 cols (t0..t0+7)
    int sg = tid >> 4;
    int tg = tid & 15;
    int s0 = sg * 4;
    int t0 = tg * 8;
    int si = s0 >> 3;
    int sj0 = s0 & 7;

    float sc[4][8];
    {   // init with position bias: p = (si-ti+7)*15 + (sj-tj+7); t<64 -> self(PE[4]), t>=64 -> dir
        const float* peb = pes + ((t0 < 64) ? 0 : cP);
        #pragma unroll
        for (int bb = 0; bb < 8; ++bb) {
            int tw = (t0 + bb) & 63;
            int ti = tw >> 3, tj = tw & 7;
            #pragma unroll
            for (int a = 0; a < 4; ++a)
                sc[a][bb] = peb[(si - ti + 7) * 15 + (sj0 + a - tj + 7)];
        }
    }

    // QK^T (Q pre-scaled by SCALE)
    int qc = 4 * (sg >> 1);
    int kc = (4 * tg) & 31;
    #pragma unroll
    for (int d4 = 0; d4 < 32; d4 += 4) {
        float4 qv[4], kv[8];
        #pragma unroll
        for (int a = 0; a < 4; ++a)
            qv[a] = *(const float4*)&Qs[(s0 + a) * 32 + ((d4 + qc) & 31)];
        #pragma unroll
        for (int bb = 0; bb < 8; ++bb)
            kv[bb] = *(const float4*)&Ks[(t0 + bb) * 32 + ((d4 + kc) & 31)];
        #pragma unroll
        for (int a = 0; a < 4; ++a)
            #pragma unroll
            for (int bb = 0; bb < 8; ++bb)
                sc[a][bb] += qv[a].x * kv[bb].x + qv[a].y * kv[bb].y
                           + qv[a].z * kv[bb].z + qv[a].w * kv[bb].w;
    }
    __syncthreads();   // Qs/Ks now dead; Ps may overwrite them

    // row softmax: 16 threads (same sg, tg=0..15) share each row -> xor-shuffles within 16 lanes
    #pragma unroll
    for (int a = 0; a < 4; ++a) {
        float m = sc[a][0];
        #pragma unroll
        for (int bb = 1; bb < 8; ++bb) m = fmaxf(m, sc[a][bb]);
        #pragma unroll
        for (int mask = 1; mask < 16; mask <<= 1) m = fmaxf(m, __shfl_xor(m, mask));
        float ssum = 0.f;
        #pragma unroll
        for (int bb = 0; bb < 8; ++bb) { sc[a][bb] = __expf(sc[a][bb] - m); ssum += sc[a][bb]; }
        #pragma unroll
        for (int mask = 1; mask < 16; mask <<= 1) ssum += __shfl_xor(ssum, mask);
        float r = 1.0f / ssum;
        #pragma unroll
        for (int bb = 0; bb < 8; ++bb) sc[a][bb] *= r;
        *(float4*)&Ps[(s0 + a) * 132 + t0]     = make_float4(sc[a][0], sc[a][1], sc[a][2], sc[a][3]);
        *(float4*)&Ps[(s0 + a) * 132 + t0 + 4] = make_float4(sc[a][4], sc[a][5], sc[a][6], sc[a][7]);
    }
    __syncthreads();

    // P (64x128) @ V (128x32); thread: 4 rows x 2 cols (d0, d0+1)
    int d0 = tg * 2;
    float oa0[4] = {0,0,0,0}, oa1[4] = {0,0,0,0};
    for (int t4 = 0; t4 < 128; t4 += 4) {
        int vc = (d0 + 4 * (t4 >> 3)) & 31;
        float4 pv[4];
        #pragma unroll
        for (int a = 0; a < 4; ++a)
            pv[a] = *(const float4*)&Ps[(s0 + a) * 132 + t4];
        float2 vv[4];
        #pragma unroll
        for (int u = 0; u < 4; ++u)
            vv[u] = *(const float2*)&Vs[(t4 + u) * 32 + vc];
        #pragma unroll
        for (int a = 0; a < 4; ++a) {
            oa0[a] += pv[a].x * vv[0].x + pv[a].y * vv[1].x + pv[a].z * vv[2].x + pv[a].w * vv[3].x;
            oa1[a] += pv[a].x * vv[0].y + pv[a].y * vv[1].y + pv[a].z * vv[2].y + pv[a].w * vv[3].y;
        }
    }

    // out[b][h*32+d][rh*8+si][rw*8+sj], 4 consecutive sj per thread -> float4
    const size_t CHW = (size_t)cH * cW;
    float* ob = out + (size_t)(b * cDIM + h * cHD) * CHW + (size_t)(rh * 8 + si) * cW + rw * 8 + sj0;
    *(float4*)(ob + (size_t)(d0    ) * CHW) = make_float4(oa0[0], oa0[1], oa0[2], oa0[3]);
    *(float4*)(ob + (size_t)(d0 + 1) * CHW) = make_float4(oa1[0], oa1[1], oa1[2], oa1[3]);
}

extern "C" void kernel_launch(void* const* d_in, const int* in_sizes, int n_in,
                              void* d_out, int out_size, void* d_ws, size_t ws_size,
                              hipStream_t stream) {
    const float* x  = (const float*)d_in[0];
    const float* pe = (const float*)d_in[1];
    float* out = (float*)d_out;
    float* pool   = (float*)d_ws;                                        // 2*1024*384 floats = 3 MB
    int*   idxbuf = (int*)((char*)d_ws + (size_t)cB * cL * 384 * sizeof(float)); // 4096 ints

    hipLaunchKernelGGL(pool_kernel,   dim3(cB * 384 * cRH), dim3(256), 0, stream, x, pool);
    hipLaunchKernelGGL(router_kernel, dim3(cB * cL),        dim3(64),  0, stream, pool, idxbuf);
    hipLaunchKernelGGL(attn_kernel,   dim3(cNH * cB * cL),  dim3(256), 0, stream, x, pe, idxbuf, out);
}

// Round 2
// 610.818 us; speedup vs baseline: 1.0739x; 1.0739x over previous
//
#include <hip/hip_runtime.h>
#include <math.h>

namespace {
constexpr int cB   = 2;
constexpr int cDIM = 192;
constexpr int cNH  = 6;
constexpr int cHD  = 32;
constexpr int cH   = 256;
constexpr int cW   = 256;
constexpr int cRH  = 32;
constexpr int cL   = 1024;   // RH*RW windows
constexpr int cP   = 225;    // (2*8-1)^2
constexpr float cSCALE = 0.17677669529663688f; // 32^-0.5
}

typedef _Float16 h8 __attribute__((ext_vector_type(8)));
typedef _Float16 h4 __attribute__((ext_vector_type(4)));
typedef float    f4 __attribute__((ext_vector_type(4)));

// ---------------- Kernel 1: 8x8 window mean-pool of q,k channels ----------------
// pool layout: [b][l][384]  (c<192: q-mean, c>=192: k-mean)
__global__ void pool_kernel(const float* __restrict__ x, float* __restrict__ pool) {
    int blk = blockIdx.x;              // b*384*32 + c*32 + rh
    int rh = blk & 31;
    int c  = (blk >> 5) % 384;
    int b  = blk / (384 * 32);
    int tid = threadIdx.x;             // 256
    int i  = tid >> 5;                 // row in window 0..7
    int rw = tid & 31;                 // window col 0..31
    const float* row = x + (((size_t)(b * 576 + c)) * cH + rh * 8 + i) * cW + rw * 8;
    float4 a0 = *(const float4*)row;
    float4 a1 = *(const float4*)(row + 4);
    float s = a0.x + a0.y + a0.z + a0.w + a1.x + a1.y + a1.z + a1.w;
    __shared__ float red[8][33];
    red[i][rw] = s;
    __syncthreads();
    if (tid < 32) {
        float t = 0.f;
        #pragma unroll
        for (int k = 0; k < 8; ++k) t += red[k][tid];
        pool[((size_t)(b * cL) + rh * 32 + tid) * 384 + c] = t * (1.0f / 64.0f);
    }
}

// ---------------- Kernel 2: router (9-neighbor argmax) ----------------
__global__ void router_kernel(const float* __restrict__ pool, int* __restrict__ idxbuf) {
    int blk = blockIdx.x;              // b*L + l
    int l = blk & (cL - 1);
    int b = blk >> 10;
    int rh = l >> 5, rw = l & 31;
    int lane = threadIdx.x;            // 64 threads = 1 wave
    int ln[9];
    #pragma unroll
    for (int n = 0; n < 9; ++n) {
        int nh = rh + n / 3 - 1;
        int nw = rw + n % 3 - 1;
        nh = nh < 0 ? 1 : (nh > 31 ? 30 : nh);   // np.pad reflect, pad=1
        nw = nw < 0 ? 1 : (nw > 31 ? 30 : nw);
        ln[n] = nh * 32 + nw;
    }
    float acc[9] = {0,0,0,0,0,0,0,0,0};
    const float* qb = pool + ((size_t)(b * cL) + l) * 384;
    #pragma unroll
    for (int ci = 0; ci < 3; ++ci) {
        int c = lane + ci * 64;
        float q = qb[c];
        #pragma unroll
        for (int n = 0; n < 9; ++n)
            acc[n] += q * pool[((size_t)(b * cL) + ln[n]) * 384 + 192 + c];
    }
    #pragma unroll
    for (int n = 0; n < 9; ++n)
        #pragma unroll
        for (int off = 32; off > 0; off >>= 1)
            acc[n] += __shfl_down(acc[n], off);
    if (lane == 0) {
        acc[4] -= 100.0f;
        int bi = 0; float bv = acc[0];
        #pragma unroll
        for (int n = 1; n < 9; ++n) if (acc[n] > bv) { bv = acc[n]; bi = n; } // first-max
        idxbuf[blk * 2]     = bi;
        idxbuf[blk * 2 + 1] = ln[bi];
    }
}

// ---------------- Kernel 3: MFMA attention, one block per (b,l,h) ----------------
// S^T = K_g * Q^T  (16x16x32 f16 MFMA, K=d=32 in one step)
// O^T = V_g^T * P^T, P^T round-trips through a wave-local LDS strip.
__global__ __launch_bounds__(256, 3) void attn_kernel(
    const float* __restrict__ x, const float* __restrict__ pe,
    const int* __restrict__ idxbuf, float* __restrict__ out)
{
    __shared__ _Float16 Qh[64 * 40];        // [s][d] pitch 40
    __shared__ _Float16 Kh[128 * 40];       // [t][d] pitch 40 (self rows 0..63, dir 64..127)
    __shared__ _Float16 Vt[32 * 136];       // [d][t] pitch 136
    __shared__ _Float16 Pst[4][16 * 136];   // per-wave [s][t] pitch 136
    __shared__ float    pes[2 * cP];        // self bias table, dir bias table

    int blk = blockIdx.x;              // h*2048 + b*1024 + l
    int h  = blk >> 11;
    int bl = blk & 2047;
    int b  = bl >> 10;
    int l  = bl & 1023;
    int rh = l >> 5, rw = l & 31;
    int tid = threadIdx.x;

    int dir  = idxbuf[bl * 2];
    int lwin = idxbuf[bl * 2 + 1];
    int rh2 = lwin >> 5, rw2 = lwin & 31;

    // ---- stage bias tables ----
    const float* pe_self = pe + (4 * cNH + h) * cP;
    const float* pe_dir  = pe + (dir * cNH + h) * cP;
    for (int t = tid; t < 2 * cP; t += 256)
        pes[t] = (t < cP) ? pe_self[t] : pe_dir[t - cP];

    // ---- stage Q, K_self, K_dir (scalar f16 writes, transposed) + V (vector writes) ----
    {
        int d = tid & 31;
        int i = tid >> 5;              // window row 0..7
        const size_t CHW = (size_t)cH * cW;
        const float* xb = x + (size_t)b * (3 * cDIM) * CHW;
        size_t off_self = (size_t)(rh  * 8 + i) * cW + rw  * 8;
        size_t off_dir  = (size_t)(rh2 * 8 + i) * cW + rw2 * 8;
        size_t cq = (size_t)(h * cHD + d) * CHW;
        size_t ck = cq + (size_t)cDIM * CHW;
        size_t cv = ck + (size_t)cDIM * CHW;

        // Q (pre-scaled)
        {
            float4 a0 = *(const float4*)(xb + cq + off_self);
            float4 a1 = *(const float4*)(xb + cq + off_self + 4);
            float vv[8] = {a0.x,a0.y,a0.z,a0.w,a1.x,a1.y,a1.z,a1.w};
            #pragma unroll
            for (int j = 0; j < 8; ++j)
                Qh[(i * 8 + j) * 40 + d] = (_Float16)(vv[j] * cSCALE);
        }
        // K self / dir
        {
            float4 a0 = *(const float4*)(xb + ck + off_self);
            float4 a1 = *(const float4*)(xb + ck + off_self + 4);
            float vv[8] = {a0.x,a0.y,a0.z,a0.w,a1.x,a1.y,a1.z,a1.w};
            #pragma unroll
            for (int j = 0; j < 8; ++j)
                Kh[(i * 8 + j) * 40 + d] = (_Float16)vv[j];
            float4 b0 = *(const float4*)(xb + ck + off_dir);
            float4 b1 = *(const float4*)(xb + ck + off_dir + 4);
            float ww[8] = {b0.x,b0.y,b0.z,b0.w,b1.x,b1.y,b1.z,b1.w};
            #pragma unroll
            for (int j = 0; j < 8; ++j)
                Kh[(64 + i * 8 + j) * 40 + d] = (_Float16)ww[j];
        }
        // V self / dir -> Vt[d][t] (t contiguous: b128 writes)
        {
            float4 a0 = *(const float4*)(xb + cv + off_self);
            float4 a1 = *(const float4*)(xb + cv + off_self + 4);
            h8 hv = { (_Float16)a0.x,(_Float16)a0.y,(_Float16)a0.z,(_Float16)a0.w,
                      (_Float16)a1.x,(_Float16)a1.y,(_Float16)a1.z,(_Float16)a1.w };
            *(h8*)&Vt[d * 136 + i * 8] = hv;
            float4 b0 = *(const float4*)(xb + cv + off_dir);
            float4 b1 = *(const float4*)(xb + cv + off_dir + 4);
            h8 hw = { (_Float16)b0.x,(_Float16)b0.y,(_Float16)b0.z,(_Float16)b0.w,
                      (_Float16)b1.x,(_Float16)b1.y,(_Float16)b1.z,(_Float16)b1.w };
            *(h8*)&Vt[d * 136 + 64 + i * 8] = hw;
        }
    }
    __syncthreads();   // the only block-wide barrier

    int lane = tid & 63;
    int w    = tid >> 6;               // wave id: s-strip 16w..16w+15
    int g    = lane >> 4;              // k-chunk group 0..3
    int sl   = lane & 15;              // s within strip / MFMA col
    int s_global = w * 16 + sl;

    // ---- bias gather offsets ----
    int base0 = ((s_global >> 3) + 7) * 15 + (s_global & 7) + 7;
    int offs[4];
    #pragma unroll
    for (int q = 0; q < 4; ++q) {
        int gq = 4 * g + q;
        offs[q] = (gq >> 3) * 15 + (gq & 7);
    }

    // ---- QK^T: S^T = K_g * Q^T, bias preloaded into the accumulator ----
    h8 qf = *(const h8*)&Qh[s_global * 40 + g * 8];
    f4 ST[8];
    #pragma unroll
    for (int T = 0; T < 8; ++T) {
        int base = ((T < 4) ? 0 : cP) + base0 - (T & 3) * 30;   // (T&3)*2*15
        f4 c;
        #pragma unroll
        for (int q = 0; q < 4; ++q) c[q] = pes[base - offs[q]];
        h8 kf = *(const h8*)&Kh[(T * 16 + sl) * 40 + g * 8];
        ST[T] = __builtin_amdgcn_mfma_f32_16x16x32_f16(kf, qf, c, 0, 0, 0);
    }

    // ---- softmax over t (lane holds 32 of 128 t for its s; partners at xor 16/32) ----
    float mx = -1e30f;
    #pragma unroll
    for (int T = 0; T < 8; ++T)
        #pragma unroll
        for (int q = 0; q < 4; ++q) mx = fmaxf(mx, ST[T][q]);
    mx = fmaxf(mx, __shfl_xor(mx, 16));
    mx = fmaxf(mx, __shfl_xor(mx, 32));
    float sum = 0.f;
    #pragma unroll
    for (int T = 0; T < 8; ++T)
        #pragma unroll
        for (int q = 0; q < 4; ++q) { float e = __expf(ST[T][q] - mx); ST[T][q] = e; sum += e; }
    sum += __shfl_xor(sum, 16);
    sum += __shfl_xor(sum, 32);
    float r = 1.0f / sum;

    // ---- P^T to wave-local LDS strip (contiguous along t: b64 writes) ----
    _Float16* prow = &Pst[w][sl * 136];
    #pragma unroll
    for (int T = 0; T < 8; ++T) {
        h4 p = { (_Float16)(ST[T][0] * r), (_Float16)(ST[T][1] * r),
                 (_Float16)(ST[T][2] * r), (_Float16)(ST[T][3] * r) };
        *(h4*)&prow[T * 16 + g * 4] = p;
    }

    // ---- PV: O^T = V_g^T * P^T ----
    f4 O0 = {0.f,0.f,0.f,0.f}, O1 = {0.f,0.f,0.f,0.f};
    #pragma unroll
    for (int kb = 0; kb < 4; ++kb) {
        h8 pf = *(const h8*)&Pst[w][sl * 136 + kb * 32 + g * 8];
        h8 v0 = *(const h8*)&Vt[ sl       * 136 + kb * 32 + g * 8];
        h8 v1 = *(const h8*)&Vt[(16 + sl) * 136 + kb * 32 + g * 8];
        O0 = __builtin_amdgcn_mfma_f32_16x16x32_f16(v0, pf, O0, 0, 0, 0);
        O1 = __builtin_amdgcn_mfma_f32_16x16x32_f16(v1, pf, O1, 0, 0, 0);
    }

    // ---- store: lane holds O[s_global][d = 16*dt + 4g + q] ----
    const size_t CHW = (size_t)cH * cW;
    int pr = rh * 8 + (s_global >> 3);
    int pc = rw * 8 + (s_global & 7);
    float* ob = out + ((size_t)(b * cDIM + h * cHD)) * CHW + (size_t)pr * cW + pc;
    #pragma unroll
    for (int q = 0; q < 4; ++q) {
        ob[(size_t)(4 * g + q) * CHW]      = O0[q];
        ob[(size_t)(16 + 4 * g + q) * CHW] = O1[q];
    }
}

extern "C" void kernel_launch(void* const* d_in, const int* in_sizes, int n_in,
                              void* d_out, int out_size, void* d_ws, size_t ws_size,
                              hipStream_t stream) {
    const float* x  = (const float*)d_in[0];
    const float* pe = (const float*)d_in[1];
    float* out = (float*)d_out;
    float* pool   = (float*)d_ws;                                        // 2*1024*384 floats = 3 MB
    int*   idxbuf = (int*)((char*)d_ws + (size_t)cB * cL * 384 * sizeof(float)); // 4096 ints

    hipLaunchKernelGGL(pool_kernel,   dim3(cB * 384 * cRH), dim3(256), 0, stream, x, pool);
    hipLaunchKernelGGL(router_kernel, dim3(cB * cL),        dim3(64),  0, stream, pool, idxbuf);
    hipLaunchKernelGGL(attn_kernel,   dim3(cNH * cB * cL),  dim3(256), 0, stream, x, pe, idxbuf, out);
}

// Round 3
// 552.853 us; speedup vs baseline: 1.1865x; 1.1048x over previous
//
#include <hip/hip_runtime.h>
#include <math.h>

namespace {
constexpr int cB   = 2;
constexpr int cDIM = 192;
constexpr int cNH  = 6;
constexpr int cHD  = 32;
constexpr int cH   = 256;
constexpr int cW   = 256;
constexpr int cRH  = 32;
constexpr int cL   = 1024;   // RH*RW windows
constexpr int cP   = 225;    // (2*8-1)^2
constexpr float cSCALE = 0.17677669529663688f; // 32^-0.5
}

typedef _Float16 h8 __attribute__((ext_vector_type(8)));
typedef _Float16 h4 __attribute__((ext_vector_type(4)));
typedef float    f4 __attribute__((ext_vector_type(4)));

// ============================================================================
// FAST PATH
// ============================================================================

// ---- Kernel T: layout transform (x fp32 -> window-major f16) + fused pool ----
// grid: b(2) x tensor(3) x head(6) x rh(32) x rw4(8)  = 9216 blocks, 256 thr
// QT/KT: [b][h][l][s=64][d=32] f16 (Q pre-scaled by SCALE); VT: [b][h][l][d=32][t=64]
__global__ __launch_bounds__(256, 6) void transform_kernel(
    const float* __restrict__ x, float* __restrict__ pool,
    _Float16* __restrict__ QT, _Float16* __restrict__ KT, _Float16* __restrict__ VT)
{
    __shared__ _Float16 Ls[4 * 64 * 40];   // [l_local*64+s][d] pitch 40

    int blk = blockIdx.x;
    int rw4 = blk & 7;
    int rhh = (blk >> 3) & 31;
    int r   = blk >> 8;
    int h = r % 6; r /= 6;
    int t = r % 3;
    int b = r / 3;
    int tid  = threadIdx.x;
    int lane = tid & 63;
    int hh   = lane >> 3;        // row within window
    int ww4  = lane & 7;         // float4 index within 32-col strip (4 windows)
    int c0   = t * cDIM + h * 32;
    int l0   = rhh * 32 + rw4 * 4;

    const size_t CHW = (size_t)cH * cW;
    size_t vbase = ((size_t)(b * cNH + h) * cL) * 2048;   // for t==2

    #pragma unroll
    for (int k = 0; k < 8; ++k) {
        int c = (tid >> 6) + 4 * k;          // wave-uniform channel 0..31
        const float* src = x + ((size_t)(b * 3 * cDIM + c0 + c)) * CHW
                         + (size_t)(rhh * 8 + hh) * cW + rw4 * 32 + ww4 * 4;
        float4 v = *(const float4*)src;

        if (t < 2) {
            // fused pool: window mean over 8x8 (q,k only, unscaled)
            float ps = v.x + v.y + v.z + v.w;
            ps += __shfl_xor(ps, 1);    // merge ww4 pairs (one window)
            ps += __shfl_xor(ps, 8);    // merge hh
            ps += __shfl_xor(ps, 16);
            ps += __shfl_xor(ps, 32);
            if ((lane & 1) == 0 && lane < 8) {
                int w = lane >> 1;
                pool[((size_t)(b * cL) + l0 + w) * 384 + t * 192 + h * 32 + c] = ps * (1.0f / 64.0f);
            }
            // stage transposed into LDS: [l_local*64 + s][d=c]
            float sc = (t == 0) ? cSCALE : 1.0f;
            int ll = ww4 >> 1;
            int s0 = hh * 8 + (ww4 & 1) * 4;
            float vv[4] = {v.x, v.y, v.z, v.w};
            #pragma unroll
            for (int j = 0; j < 4; ++j)
                Ls[(ll * 64 + s0 + j) * 40 + c] = (_Float16)(vv[j] * sc);
        } else {
            // V: direct write, [l][d][t] with t contiguous
            int ll = ww4 >> 1;
            int tt = hh * 8 + (ww4 & 1) * 4;
            h4 hv = { (_Float16)v.x, (_Float16)v.y, (_Float16)v.z, (_Float16)v.w };
            *(h4*)&VT[vbase + (size_t)(l0 + ll) * 2048 + c * 64 + tt] = hv;
        }
    }

    if (t < 2) {
        __syncthreads();
        _Float16* dst = (t == 0) ? QT : KT;
        size_t obase = ((size_t)(b * cNH + h) * cL) * 2048;
        #pragma unroll
        for (int j = 0; j < 4; ++j) {
            int linear = tid + 256 * j;       // (l_local, s, d8)
            int ll = linear >> 8;
            int s  = (linear >> 2) & 63;
            int d8 = linear & 3;
            h8 val = *(const h8*)&Ls[(ll * 64 + s) * 40 + d8 * 8];
            *(h8*)&dst[obase + (size_t)(l0 + ll) * 2048 + s * 32 + d8 * 8] = val;
        }
    }
}

// ---------------- Router (9-neighbor argmax) ----------------
__global__ void router_kernel(const float* __restrict__ pool, int* __restrict__ idxbuf) {
    int blk = blockIdx.x;              // b*L + l
    int l = blk & (cL - 1);
    int b = blk >> 10;
    int rh = l >> 5, rw = l & 31;
    int lane = threadIdx.x;            // 64 threads = 1 wave
    int ln[9];
    #pragma unroll
    for (int n = 0; n < 9; ++n) {
        int nh = rh + n / 3 - 1;
        int nw = rw + n % 3 - 1;
        nh = nh < 0 ? 1 : (nh > 31 ? 30 : nh);   // np.pad reflect, pad=1
        nw = nw < 0 ? 1 : (nw > 31 ? 30 : nw);
        ln[n] = nh * 32 + nw;
    }
    float acc[9] = {0,0,0,0,0,0,0,0,0};
    const float* qb = pool + ((size_t)(b * cL) + l) * 384;
    #pragma unroll
    for (int ci = 0; ci < 3; ++ci) {
        int c = lane + ci * 64;
        float q = qb[c];
        #pragma unroll
        for (int n = 0; n < 9; ++n)
            acc[n] += q * pool[((size_t)(b * cL) + ln[n]) * 384 + 192 + c];
    }
    #pragma unroll
    for (int n = 0; n < 9; ++n)
        #pragma unroll
        for (int off = 32; off > 0; off >>= 1)
            acc[n] += __shfl_down(acc[n], off);
    if (lane == 0) {
        acc[4] -= 100.0f;
        int bi = 0; float bv = acc[0];
        #pragma unroll
        for (int n = 1; n < 9; ++n) if (acc[n] > bv) { bv = acc[n]; bi = n; } // first-max
        idxbuf[blk * 2]     = bi;
        idxbuf[blk * 2 + 1] = ln[bi];
    }
}

// ---- Kernel A: MFMA attention from window-major f16, one block per (b,l,h) ----
// All Q/K/V fragments load straight from global (coalesced h8); LDS only for
// bias table + per-wave P^T strip.
__global__ __launch_bounds__(256, 5) void attn_kernel(
    const _Float16* __restrict__ QT, const _Float16* __restrict__ KT,
    const _Float16* __restrict__ VT, const float* __restrict__ pe,
    const int* __restrict__ idxbuf, float* __restrict__ out)
{
    __shared__ float    pes[2 * cP];
    __shared__ _Float16 Pst[4][16 * 136];

    int blk = blockIdx.x;              // h*2048 + b*1024 + l
    int h  = blk >> 11;
    int bl = blk & 2047;
    int b  = bl >> 10;
    int l  = bl & 1023;
    int rh = l >> 5, rw = l & 31;
    int tid = threadIdx.x;

    int dir  = idxbuf[bl * 2];
    int lwin = idxbuf[bl * 2 + 1];

    const float* pe_self = pe + (4 * cNH + h) * cP;
    const float* pe_dir  = pe + (dir * cNH + h) * cP;
    for (int tt = tid; tt < 2 * cP; tt += 256)
        pes[tt] = (tt < cP) ? pe_self[tt] : pe_dir[tt - cP];
    __syncthreads();

    int lane = tid & 63;
    int w    = tid >> 6;               // wave id: s-strip 16w..16w+15
    int g    = lane >> 4;              // k-chunk group 0..3
    int sl   = lane & 15;              // s within strip / MFMA col
    int s_global = w * 16 + sl;

    size_t base  = ((size_t)(b * cNH + h) * cL + l)    * 2048;
    size_t baseD = ((size_t)(b * cNH + h) * cL + lwin) * 2048;

    // bias gather offsets
    int base0 = ((s_global >> 3) + 7) * 15 + (s_global & 7) + 7;
    int offs[4];
    #pragma unroll
    for (int q = 0; q < 4; ++q) {
        int gq = 4 * g + q;
        offs[q] = (gq >> 3) * 15 + (gq & 7);
    }

    // ---- QK^T: S^T = K_g * Q^T, bias preloaded into accumulator ----
    h8 qf = *(const h8*)&QT[base + s_global * 32 + g * 8];
    f4 ST[8];
    #pragma unroll
    for (int T = 0; T < 8; ++T) {
        int bias = ((T < 4) ? 0 : cP) + base0 - (T & 3) * 30;
        f4 c;
        #pragma unroll
        for (int q = 0; q < 4; ++q) c[q] = pes[bias - offs[q]];
        h8 kf = (T < 4)
            ? *(const h8*)&KT[base  + (T * 16 + sl) * 32 + g * 8]
            : *(const h8*)&KT[baseD + ((T - 4) * 16 + sl) * 32 + g * 8];
        ST[T] = __builtin_amdgcn_mfma_f32_16x16x32_f16(kf, qf, c, 0, 0, 0);
    }

    // ---- softmax over t (lane holds 32 of 128 t for its s) ----
    float mx = -1e30f;
    #pragma unroll
    for (int T = 0; T < 8; ++T)
        #pragma unroll
        for (int q = 0; q < 4; ++q) mx = fmaxf(mx, ST[T][q]);
    mx = fmaxf(mx, __shfl_xor(mx, 16));
    mx = fmaxf(mx, __shfl_xor(mx, 32));
    float sum = 0.f;
    #pragma unroll
    for (int T = 0; T < 8; ++T)
        #pragma unroll
        for (int q = 0; q < 4; ++q) { float e = __expf(ST[T][q] - mx); ST[T][q] = e; sum += e; }
    sum += __shfl_xor(sum, 16);
    sum += __shfl_xor(sum, 32);
    float r = 1.0f / sum;

    // ---- P^T to wave-local LDS strip ----
    _Float16* prow = &Pst[w][sl * 136];
    #pragma unroll
    for (int T = 0; T < 8; ++T) {
        h4 p = { (_Float16)(ST[T][0] * r), (_Float16)(ST[T][1] * r),
                 (_Float16)(ST[T][2] * r), (_Float16)(ST[T][3] * r) };
        *(h4*)&prow[T * 16 + g * 4] = p;
    }

    // ---- PV: O^T = V_g^T * P^T ----
    f4 O0 = {0.f,0.f,0.f,0.f}, O1 = {0.f,0.f,0.f,0.f};
    #pragma unroll
    for (int kb = 0; kb < 4; ++kb) {
        h8 pf = *(const h8*)&Pst[w][sl * 136 + kb * 32 + g * 8];
        size_t vb = (kb < 2) ? (base  + (kb * 32 + g * 8))
                             : (baseD + ((kb - 2) * 32 + g * 8));
        h8 v0 = *(const h8*)&VT[vb + sl * 64];
        h8 v1 = *(const h8*)&VT[vb + (16 + sl) * 64];
        O0 = __builtin_amdgcn_mfma_f32_16x16x32_f16(v0, pf, O0, 0, 0, 0);
        O1 = __builtin_amdgcn_mfma_f32_16x16x32_f16(v1, pf, O1, 0, 0, 0);
    }

    // ---- store ----
    const size_t CHW = (size_t)cH * cW;
    int pr = rh * 8 + (s_global >> 3);
    int pc = rw * 8 + (s_global & 7);
    float* ob = out + ((size_t)(b * cDIM + h * cHD)) * CHW + (size_t)pr * cW + pc;
    #pragma unroll
    for (int q = 0; q < 4; ++q) {
        ob[(size_t)(4 * g + q) * CHW]      = O0[q];
        ob[(size_t)(16 + 4 * g + q) * CHW] = O1[q];
    }
}

// ============================================================================
// FALLBACK PATH (round-2 kernels, used only if ws_size is too small)
// ============================================================================

__global__ void pool_kernel(const float* __restrict__ x, float* __restrict__ pool) {
    int blk = blockIdx.x;
    int rh = blk & 31;
    int c  = (blk >> 5) % 384;
    int b  = blk / (384 * 32);
    int tid = threadIdx.x;
    int i  = tid >> 5;
    int rw = tid & 31;
    const float* row = x + (((size_t)(b * 576 + c)) * cH + rh * 8 + i) * cW + rw * 8;
    float4 a0 = *(const float4*)row;
    float4 a1 = *(const float4*)(row + 4);
    float s = a0.x + a0.y + a0.z + a0.w + a1.x + a1.y + a1.z + a1.w;
    __shared__ float red[8][33];
    red[i][rw] = s;
    __syncthreads();
    if (tid < 32) {
        float t = 0.f;
        #pragma unroll
        for (int k = 0; k < 8; ++k) t += red[k][tid];
        pool[((size_t)(b * cL) + rh * 32 + tid) * 384 + c] = t * (1.0f / 64.0f);
    }
}

__global__ __launch_bounds__(256, 3) void attn_old_kernel(
    const float* __restrict__ x, const float* __restrict__ pe,
    const int* __restrict__ idxbuf, float* __restrict__ out)
{
    __shared__ _Float16 Qh[64 * 40];
    __shared__ _Float16 Kh[128 * 40];
    __shared__ _Float16 Vt[32 * 136];
    __shared__ _Float16 Pst[4][16 * 136];
    __shared__ float    pes[2 * cP];

    int blk = blockIdx.x;
    int h  = blk >> 11;
    int bl = blk & 2047;
    int b  = bl >> 10;
    int l  = bl & 1023;
    int rh = l >> 5, rw = l & 31;
    int tid = threadIdx.x;

    int dir  = idxbuf[bl * 2];
    int lwin = idxbuf[bl * 2 + 1];
    int rh2 = lwin >> 5, rw2 = lwin & 31;

    const float* pe_self = pe + (4 * cNH + h) * cP;
    const float* pe_dir  = pe + (dir * cNH + h) * cP;
    for (int t = tid; t < 2 * cP; t += 256)
        pes[t] = (t < cP) ? pe_self[t] : pe_dir[t - cP];

    {
        int d = tid & 31;
        int i = tid >> 5;
        const size_t CHW = (size_t)cH * cW;
        const float* xb = x + (size_t)b * (3 * cDIM) * CHW;
        size_t off_self = (size_t)(rh  * 8 + i) * cW + rw  * 8;
        size_t off_dir  = (size_t)(rh2 * 8 + i) * cW + rw2 * 8;
        size_t cq = (size_t)(h * cHD + d) * CHW;
        size_t ck = cq + (size_t)cDIM * CHW;
        size_t cv = ck + (size_t)cDIM * CHW;
        {
            float4 a0 = *(const float4*)(xb + cq + off_self);
            float4 a1 = *(const float4*)(xb + cq + off_self + 4);
            float vv[8] = {a0.x,a0.y,a0.z,a0.w,a1.x,a1.y,a1.z,a1.w};
            #pragma unroll
            for (int j = 0; j < 8; ++j) Qh[(i * 8 + j) * 40 + d] = (_Float16)(vv[j] * cSCALE);
        }
        {
            float4 a0 = *(const float4*)(xb + ck + off_self);
            float4 a1 = *(const float4*)(xb + ck + off_self + 4);
            float vv[8] = {a0.x,a0.y,a0.z,a0.w,a1.x,a1.y,a1.z,a1.w};
            #pragma unroll
            for (int j = 0; j < 8; ++j) Kh[(i * 8 + j) * 40 + d] = (_Float16)vv[j];
            float4 b0 = *(const float4*)(xb + ck + off_dir);
            float4 b1 = *(const float4*)(xb + ck + off_dir + 4);
            float ww[8] = {b0.x,b0.y,b0.z,b0.w,b1.x,b1.y,b1.z,b1.w};
            #pragma unroll
            for (int j = 0; j < 8; ++j) Kh[(64 + i * 8 + j) * 40 + d] = (_Float16)ww[j];
        }
        {
            float4 a0 = *(const float4*)(xb + cv + off_self);
            float4 a1 = *(const float4*)(xb + cv + off_self + 4);
            h8 hv = { (_Float16)a0.x,(_Float16)a0.y,(_Float16)a0.z,(_Float16)a0.w,
                      (_Float16)a1.x,(_Float16)a1.y,(_Float16)a1.z,(_Float16)a1.w };
            *(h8*)&Vt[d * 136 + i * 8] = hv;
            float4 b0 = *(const float4*)(xb + cv + off_dir);
            float4 b1 = *(const float4*)(xb + cv + off_dir + 4);
            h8 hw = { (_Float16)b0.x,(_Float16)b0.y,(_Float16)b0.z,(_Float16)b0.w,
                      (_Float16)b1.x,(_Float16)b1.y,(_Float16)b1.z,(_Float16)b1.w };
            *(h8*)&Vt[d * 136 + 64 + i * 8] = hw;
        }
    }
    __syncthreads();

    int lane = tid & 63;
    int w    = tid >> 6;
    int g    = lane >> 4;
    int sl   = lane & 15;
    int s_global = w * 16 + sl;

    int base0 = ((s_global >> 3) + 7) * 15 + (s_global & 7) + 7;
    int offs[4];
    #pragma unroll
    for (int q = 0; q < 4; ++q) {
        int gq = 4 * g + q;
        offs[q] = (gq >> 3) * 15 + (gq & 7);
    }

    h8 qf = *(const h8*)&Qh[s_global * 40 + g * 8];
    f4 ST[8];
    #pragma unroll
    for (int T = 0; T < 8; ++T) {
        int bias = ((T < 4) ? 0 : cP) + base0 - (T & 3) * 30;
        f4 c;
        #pragma unroll
        for (int q = 0; q < 4; ++q) c[q] = pes[bias - offs[q]];
        h8 kf = *(const h8*)&Kh[(T * 16 + sl) * 40 + g * 8];
        ST[T] = __builtin_amdgcn_mfma_f32_16x16x32_f16(kf, qf, c, 0, 0, 0);
    }

    float mx = -1e30f;
    #pragma unroll
    for (int T = 0; T < 8; ++T)
        #pragma unroll
        for (int q = 0; q < 4; ++q) mx = fmaxf(mx, ST[T][q]);
    mx = fmaxf(mx, __shfl_xor(mx, 16));
    mx = fmaxf(mx, __shfl_xor(mx, 32));
    float sum = 0.f;
    #pragma unroll
    for (int T = 0; T < 8; ++T)
        #pragma unroll
        for (int q = 0; q < 4; ++q) { float e = __expf(ST[T][q] - mx); ST[T][q] = e; sum += e; }
    sum += __shfl_xor(sum, 16);
    sum += __shfl_xor(sum, 32);
    float r = 1.0f / sum;

    _Float16* prow = &Pst[w][sl * 136];
    #pragma unroll
    for (int T = 0; T < 8; ++T) {
        h4 p = { (_Float16)(ST[T][0] * r), (_Float16)(ST[T][1] * r),
                 (_Float16)(ST[T][2] * r), (_Float16)(ST[T][3] * r) };
        *(h4*)&prow[T * 16 + g * 4] = p;
    }

    f4 O0 = {0.f,0.f,0.f,0.f}, O1 = {0.f,0.f,0.f,0.f};
    #pragma unroll
    for (int kb = 0; kb < 4; ++kb) {
        h8 pf = *(const h8*)&Pst[w][sl * 136 + kb * 32 + g * 8];
        h8 v0 = *(const h8*)&Vt[ sl       * 136 + kb * 32 + g * 8];
        h8 v1 = *(const h8*)&Vt[(16 + sl) * 136 + kb * 32 + g * 8];
        O0 = __builtin_amdgcn_mfma_f32_16x16x32_f16(v0, pf, O0, 0, 0, 0);
        O1 = __builtin_amdgcn_mfma_f32_16x16x32_f16(v1, pf, O1, 0, 0, 0);
    }

    const size_t CHW = (size_t)cH * cW;
    int pr = rh * 8 + (s_global >> 3);
    int pc = rw * 8 + (s_global & 7);
    float* ob = out + ((size_t)(b * cDIM + h * cHD)) * CHW + (size_t)pr * cW + pc;
    #pragma unroll
    for (int q = 0; q < 4; ++q) {
        ob[(size_t)(4 * g + q) * CHW]      = O0[q];
        ob[(size_t)(16 + 4 * g + q) * CHW] = O1[q];
    }
}

// ============================================================================

extern "C" void kernel_launch(void* const* d_in, const int* in_sizes, int n_in,
                              void* d_out, int out_size, void* d_ws, size_t ws_size,
                              hipStream_t stream) {
    const float* x  = (const float*)d_in[0];
    const float* pe = (const float*)d_in[1];
    float* out = (float*)d_out;

    const size_t OFF_POOL = 0;
    const size_t OFF_IDX  = (size_t)cB * cL * 384 * sizeof(float);        // 3 MB
    const size_t OFF_QT   = OFF_IDX + 16384;
    const size_t SZ_T     = (size_t)cB * cNH * cL * 2048 * sizeof(_Float16); // 50.3 MB
    const size_t OFF_KT   = OFF_QT + SZ_T;
    const size_t OFF_VT   = OFF_KT + SZ_T;
    const size_t NEED     = OFF_VT + SZ_T;

    float* pool   = (float*)((char*)d_ws + OFF_POOL);
    int*   idxbuf = (int*)((char*)d_ws + OFF_IDX);

    if (ws_size >= NEED) {
        _Float16* QT = (_Float16*)((char*)d_ws + OFF_QT);
        _Float16* KT = (_Float16*)((char*)d_ws + OFF_KT);
        _Float16* VT = (_Float16*)((char*)d_ws + OFF_VT);
        hipLaunchKernelGGL(transform_kernel, dim3(cB * 3 * cNH * cRH * 8), dim3(256), 0, stream,
                           x, pool, QT, KT, VT);
        hipLaunchKernelGGL(router_kernel,    dim3(cB * cL),  dim3(64),  0, stream, pool, idxbuf);
        hipLaunchKernelGGL(attn_kernel,      dim3(cNH * cB * cL), dim3(256), 0, stream,
                           QT, KT, VT, pe, idxbuf, out);
    } else {
        hipLaunchKernelGGL(pool_kernel,     dim3(cB * 384 * cRH), dim3(256), 0, stream, x, pool);
        hipLaunchKernelGGL(router_kernel,   dim3(cB * cL),        dim3(64),  0, stream, pool, idxbuf);
        hipLaunchKernelGGL(attn_old_kernel, dim3(cNH * cB * cL),  dim3(256), 0, stream, x, pe, idxbuf, out);
    }
}